// Round 4
// baseline (471.667 us; speedup 1.0000x reference)
//
#include <hip/hip_runtime.h>

// AREMA envelope follower: y_t = y_{t-1} + alpha*(x_t - y_{t-1}),
// alpha = ATTACK if (x_t - y_{t-1}) > 0 else RELEASE.
// Segmented scan with WARM-step warm-up (contraction => bounded error).
//
// History:
//  R2: SEGS=32,  WARM=256, scalar: 176us, fetch 199MB, 2.7 TB/s, occ 19%.
//  R3: SEGS=128, WARM=256, scalar: 196us, fetch 407MB, 3.5 TB/s, occ 61%.
//      (traffic growth ate the occupancy win)
//  R4: SEGS=64,  WARM=128, scalar: 174us, fetch 196MB, 2.65 TB/s, occ 37%.
//      KEY DATA: 2x waves vs R2, same BW. Occupancy is NOT the lever;
//      in-flight bytes (~64KB/CU) already >> Little's-law need (~9KB).
//  R5: the 2.7 TB/s cap matches the 4B/lane scalar-access pattern
//      (256B/wave-instr). m13's 6.29 TB/s ceiling used float4 (16B/lane,
//      1KB/wave-instr). -> Vectorize features: each thread owns 4 consecutive
//      f (128 thr/row), dwordx4 loads + nontemporal dwordx4 stores, 4
//      independent recurrence chains/thread (ILP). Traffic plan unchanged
//      (SEGS=64, WARM=128 = 1.5x nominal reads, L3-absorbed).
//  R5b: compile fix — __builtin_nontemporal_store rejects HIP_vector_type;
//      use clang ext_vector_type(4) float instead.

#define T_LEN   16384
#define F_DIM   512
#define ROWV    (F_DIM / 4)   // 128 float4 per (b,t) row
#define SEGS    64
#define SEG_LEN 256           // T_LEN / SEGS
#define WARM    128           // multiple of 2*UNROLL
#define UNROLL  8

#define ATTACK_C  0.18126924692201818f   // 1 - exp(-0.001/0.005)
#define RELEASE_C 0.019801326696744665f  // 1 - exp(-0.001/0.05)

typedef float f32x4 __attribute__((ext_vector_type(4)));

__device__ __forceinline__ float astep(float x, float y) {
    float d = x - y;
    float alpha = (d > 0.0f) ? ATTACK_C : RELEASE_C;
    return fmaf(alpha, d, y);   // == alpha*x + (1-alpha)*y
}

__device__ __forceinline__ f32x4 astep4(f32x4 x, f32x4 y) {
    f32x4 r;
    r[0] = astep(x[0], y[0]);
    r[1] = astep(x[1], y[1]);
    r[2] = astep(x[2], y[2]);
    r[3] = astep(x[3], y[3]);
    return r;
}

__global__ __launch_bounds__(128) void arema_kernel(const f32x4* __restrict__ xg,
                                                    f32x4* __restrict__ yg) {
    const int v = threadIdx.x;      // float4 column 0..127
    const int s = blockIdx.y;       // segment
    const int b = blockIdx.z;       // batch

    const int sL    = s * SEG_LEN;
    const int begin = (sL - WARM > 0) ? (sL - WARM) : 0;
    const int end   = sL + SEG_LEN;

    const f32x4* __restrict__ xin = xg + (size_t)b * T_LEN * ROWV + v;
    f32x4* __restrict__ yout      = yg + (size_t)b * T_LEN * ROWV + v;

    f32x4 y = (f32x4)(0.f);
    f32x4 bufA[UNROLL], bufB[UNROLL];

    int t = begin;
#pragma unroll
    for (int i = 0; i < UNROLL; ++i)
        bufA[i] = xin[(size_t)(t + i) * ROWV];

    // (end - begin) is 256 (s==0) or 384 -> nch in {32,48}, always even.
    const int nch = (end - begin) / UNROLL;

    // steady pairs: full double-buffer prefetch
    for (int c = 0; c + 2 < nch; c += 2) {
        // prefetch chunk c+1 into bufB (in flight while computing bufA)
#pragma unroll
        for (int i = 0; i < UNROLL; ++i)
            bufB[i] = xin[(size_t)(t + UNROLL + i) * ROWV];

        // compute chunk c from bufA
        {
            const bool wr = (t >= sL);   // uniform: warm-up vs live
#pragma unroll
            for (int i = 0; i < UNROLL; ++i) {
                y = astep4(bufA[i], y);
                if (wr)
                    __builtin_nontemporal_store(y, &yout[(size_t)(t + i) * ROWV]);
            }
        }

        // prefetch chunk c+2 into bufA
#pragma unroll
        for (int i = 0; i < UNROLL; ++i)
            bufA[i] = xin[(size_t)(t + 2 * UNROLL + i) * ROWV];

        // compute chunk c+1 from bufB
        {
            const int tb = t + UNROLL;
            const bool wr = (tb >= sL);
#pragma unroll
            for (int i = 0; i < UNROLL; ++i) {
                y = astep4(bufB[i], y);
                if (wr)
                    __builtin_nontemporal_store(y, &yout[(size_t)(tb + i) * ROWV]);
            }
        }

        t += 2 * UNROLL;
    }

    // final pair (c == nch-2): no further prefetch needed
    {
#pragma unroll
        for (int i = 0; i < UNROLL; ++i)
            bufB[i] = xin[(size_t)(t + UNROLL + i) * ROWV];

        {
            const bool wr = (t >= sL);
#pragma unroll
            for (int i = 0; i < UNROLL; ++i) {
                y = astep4(bufA[i], y);
                if (wr)
                    __builtin_nontemporal_store(y, &yout[(size_t)(t + i) * ROWV]);
            }
        }
        {
            const int tb = t + UNROLL;
#pragma unroll
            for (int i = 0; i < UNROLL; ++i) {
                y = astep4(bufB[i], y);
                // last chunk is always live (tb >= sL by construction)
                __builtin_nontemporal_store(y, &yout[(size_t)(tb + i) * ROWV]);
            }
        }
    }
}

extern "C" void kernel_launch(void* const* d_in, const int* in_sizes, int n_in,
                              void* d_out, int out_size, void* d_ws, size_t ws_size,
                              hipStream_t stream) {
    const f32x4* x = (const f32x4*)d_in[0];
    f32x4* y = (f32x4*)d_out;
    const int B = in_sizes[0] / (T_LEN * F_DIM);    // = 8
    dim3 grid(1, SEGS, B);                          // 512 blocks x 2 waves
    arema_kernel<<<grid, dim3(128, 1, 1), 0, stream>>>(x, y);
}